// Round 2
// baseline (506.047 us; speedup 1.0000x reference)
//
#include <hip/hip_runtime.h>
#include <cstdint>
#include <cstddef>

#define LA 4096
#define LB 4096
#define DD 1024

typedef unsigned short u16;
typedef short bf16x8 __attribute__((ext_vector_type(8)));
typedef float f32x4 __attribute__((ext_vector_type(4)));

__device__ __forceinline__ u16 f2bf(float f) {
  unsigned u = __builtin_bit_cast(unsigned, f);
  u += 0x7fffu + ((u >> 16) & 1u);
  return (u16)(u >> 16);
}
__device__ __forceinline__ float bf2f(u16 h) {
  return __builtin_bit_cast(float, (unsigned)h << 16);
}
// async global->LDS, 16B/lane; lds base must be wave-uniform (HW adds lane*16)
__device__ __forceinline__ void async16(const void* g, void* l) {
  __builtin_amdgcn_global_load_lds(
      (const __attribute__((address_space(1))) unsigned int*)g,
      (__attribute__((address_space(3))) unsigned int*)l, 16, 0, 0);
}

// ---- prepass: split fp32 X -> concat-K bf16: A'=[hi|hi|lo], B'=[hi|lo|hi] --
// Turns the 3-term split GEMM into ONE standard bf16 GEMM with K=3072.
__global__ __launch_bounds__(256) void split_ab(const float* __restrict__ A,
                                                const float* __restrict__ B,
                                                u16* __restrict__ Ap,
                                                u16* __restrict__ Bp) {
  const int side = blockIdx.x >> 11;
  const size_t idx = ((size_t)(blockIdx.x & 2047) * 256 + threadIdx.x) * 8;
  const float* src = side ? B : A;
  u16* dst = side ? Bp : Ap;
  const float4 a = *(const float4*)&src[idx];
  const float4 b = *(const float4*)&src[idx + 4];
  float v[8] = {a.x, a.y, a.z, a.w, b.x, b.y, b.z, b.w};
  bf16x8 hi, lo;
#pragma unroll
  for (int i = 0; i < 8; ++i) {
    const u16 h = f2bf(v[i]);
    hi[i] = (short)h;
    lo[i] = (short)f2bf(v[i] - bf2f(h));
  }
  const size_t row = idx >> 10;
  const size_t k = idx & 1023;
  u16* base = dst + row * 3072 + k;
  *(bf16x8*)&base[0] = hi;
  *(bf16x8*)&base[side ? 2048 : 1024] = hi;
  *(bf16x8*)&base[side ? 1024 : 2048] = lo;
}

// ------- tiled transpose fp32 -> bf16: out[c][r] = bf16(in[r][c]) -----------
__global__ __launch_bounds__(256) void tr_f32(const float* __restrict__ in,
                                              u16* __restrict__ out,
                                              int R, int C) {
  __shared__ u16 t[32][33];
  const int c0 = blockIdx.x * 32, r0 = blockIdx.y * 32;
  const int tid = threadIdx.x;
  const int lr = tid >> 3, lc = (tid & 7) * 4;
  const float4 v = *(const float4*)&in[(size_t)(r0 + lr) * C + c0 + lc];
  t[lr][lc + 0] = f2bf(v.x); t[lr][lc + 1] = f2bf(v.y);
  t[lr][lc + 2] = f2bf(v.z); t[lr][lc + 3] = f2bf(v.w);
  __syncthreads();
  ushort4 w;
  w.x = t[lc + 0][lr]; w.y = t[lc + 1][lr]; w.z = t[lc + 2][lr]; w.w = t[lc + 3][lr];
  *(ushort4*)&out[(size_t)(c0 + lr) * R + r0 + lc] = w;
}

// ======= 256x256 bf16 GEMM engine: counted-vmcnt dbuf + XOR swizzle =========
// C[i][j] = sum_k A[i][k] B[j][k]; A:[M][K], B:[N][K] row-major bf16.
// 8 waves (2M x 4N), per-wave 128x64 output, BK=64, LDS 128 KiB (2 buffers).
// T2: st-swizzle cb^=((row&7)<<4) applied on pre-swizzled GLOBAL source
//     (linear global_load_lds dest) and on the ds_read address (involution).
// T4: vmcnt(8) in-loop keeps next tile's 8 loads in flight across barriers;
//     peeled vmcnt(0) on the last tile.  T5: setprio around MFMA clusters.
#define STAGE8(buf, ktile)                                                   \
  do {                                                                       \
    const size_t kb = (size_t)(ktile) * 128;                                 \
    _Pragma("unroll") for (int l = 0; l < 4; ++l)                            \
        async16(Ag8 + aoff[l] + kb, &lA[buf][ldst[l]]);                      \
    _Pragma("unroll") for (int l = 0; l < 4; ++l)                            \
        async16(Bg8 + boff[l] + kb, &lB[buf][ldst[l]]);                      \
  } while (0)

template <int ATOMIC>
__global__ __launch_bounds__(512, 2) void gemm8(const u16* __restrict__ Ag,
                                                const u16* __restrict__ Bg,
                                                const float* __restrict__ inv,
                                                float* __restrict__ C,
                                                const int K, const int ldc,
                                                const int Ksub) {
  __shared__ u16 lA[2][256 * 64];
  __shared__ u16 lB[2][256 * 64];
  const int gx = gridDim.x;
  const int nxy = gx * gridDim.y;            // 256 (energy) / 64 (PV): %8==0
  int lin = blockIdx.y * gx + blockIdx.x;
  lin = (lin & 7) * (nxy >> 3) + (lin >> 3); // XCD-bijective swizzle
  const int j0 = (lin % gx) * 256;
  const int i0 = (lin / gx) * 256;
  const int tid = threadIdx.x;
  const int lane = tid & 63, quad = lane >> 4, lq = lane & 15;
  const int wave = tid >> 6;
  const int wr = wave >> 2, wc = wave & 3;
  const char* Ag8 = (const char*)Ag;
  const char* Bg8 = (const char*)Bg;

  size_t aoff[4], boff[4];
  int ldst[4];
#pragma unroll
  for (int l = 0; l < 4; ++l) {
    const int d = l * 8192 + tid * 16;       // dest byte in 32KB tile
    const int row = d >> 7;                  // 0..255
    const int cb = (d & 127) ^ ((row & 7) << 4);  // pre-swizzled source col
    aoff[l] = ((size_t)(i0 + row) * K + (size_t)blockIdx.z * Ksub) * 2 + cb;
    boff[l] = ((size_t)(j0 + row) * K + (size_t)blockIdx.z * Ksub) * 2 + cb;
    ldst[l] = (l * 8192 + wave * 1024) >> 1; // wave-uniform LDS dest (u16 idx)
  }

  f32x4 acc[8][4] = {};
  const int NT = Ksub >> 6;
  STAGE8(0, 0);
  STAGE8(1, 1);

  for (int t = 0; t < NT; ++t) {
    const int cur = t & 1;
    if (t < NT - 1)
      asm volatile("s_waitcnt vmcnt(8)" ::: "memory");  // cur tile done, next in flight
    else
      asm volatile("s_waitcnt vmcnt(0)" ::: "memory");  // tail drain
    __builtin_amdgcn_s_barrier();
    const char* bA = (const char*)&lA[cur][0];
    const char* bB = (const char*)&lB[cur][0];
#pragma unroll
    for (int ks = 0; ks < 2; ++ks) {
      bf16x8 bfrag[4];
#pragma unroll
      for (int f = 0; f < 4; ++f) {
        const int row = wc * 64 + f * 16 + lq;
        bfrag[f] = *(const bf16x8*)(bB + row * 128 +
                                    ((ks * 64 + quad * 16) ^ ((lq & 7) << 4)));
      }
#pragma unroll
      for (int mh = 0; mh < 2; ++mh) {
        bf16x8 afrag[4];
#pragma unroll
        for (int f = 0; f < 4; ++f) {
          const int row = wr * 128 + (mh * 4 + f) * 16 + lq;
          afrag[f] = *(const bf16x8*)(bA + row * 128 +
                                      ((ks * 64 + quad * 16) ^ ((lq & 7) << 4)));
        }
        __builtin_amdgcn_s_setprio(1);
#pragma unroll
        for (int fm = 0; fm < 4; ++fm)
#pragma unroll
          for (int fn = 0; fn < 4; ++fn)
            acc[mh * 4 + fm][fn] = __builtin_amdgcn_mfma_f32_16x16x32_bf16(
                afrag[fm], bfrag[fn], acc[mh * 4 + fm][fn], 0, 0, 0);
        __builtin_amdgcn_s_setprio(0);
      }
    }
    __builtin_amdgcn_s_barrier();            // all waves done reading buf[cur]
    if (t + 2 < NT) STAGE8(cur, t + 2);      // overwrite with tile t+2
  }

#pragma unroll
  for (int fm = 0; fm < 8; ++fm) {
    const int gi = i0 + wr * 128 + fm * 16 + quad * 4;
#pragma unroll
    for (int r = 0; r < 4; ++r) {
#pragma unroll
      for (int fn = 0; fn < 4; ++fn) {
        const int gj = j0 + wc * 64 + fn * 16 + lq;
        float* p = &C[(size_t)(gi + r) * ldc + gj];
        if (ATOMIC)
          unsafeAtomicAdd(p, acc[fm][fn][r] * inv[gi + r]);
        else
          *p = acc[fm][fn][r];
      }
    }
  }
}

// ---- fused: row softmax stats + Pa[i][j]=bf16(exp(E-rmax)) + zero wave_a ---
__global__ __launch_bounds__(256) void row_softmax_pa(const float* __restrict__ E,
                                                      float* __restrict__ rinv,
                                                      u16* __restrict__ P,
                                                      float* __restrict__ wa) {
  __shared__ float red[8];
  const int row = blockIdx.x, tid = threadIdx.x;
  const float* e = E + (size_t)row * LB;
  float4 v[4];
#pragma unroll
  for (int c = 0; c < 4; ++c) v[c] = *(const float4*)&e[(c * 256 + tid) * 4];
  float m = -__builtin_inff();
#pragma unroll
  for (int c = 0; c < 4; ++c)
    m = fmaxf(m, fmaxf(fmaxf(v[c].x, v[c].y), fmaxf(v[c].z, v[c].w)));
#pragma unroll
  for (int o = 32; o > 0; o >>= 1) m = fmaxf(m, __shfl_down(m, o));
  if ((tid & 63) == 0) red[tid >> 6] = m;
  __syncthreads();
  m = fmaxf(fmaxf(red[0], red[1]), fmaxf(red[2], red[3]));
  float s = 0.f;
#pragma unroll
  for (int c = 0; c < 4; ++c)
    s += __expf(v[c].x - m) + __expf(v[c].y - m) + __expf(v[c].z - m) + __expf(v[c].w - m);
#pragma unroll
  for (int o = 32; o > 0; o >>= 1) s += __shfl_down(s, o);
  if ((tid & 63) == 0) red[4 + (tid >> 6)] = s;
  __syncthreads();
  if (tid == 0) rinv[row] = 1.f / (red[4] + red[5] + red[6] + red[7]);
#pragma unroll
  for (int c = 0; c < 4; ++c) {
    ushort4 w;
    w.x = f2bf(__expf(v[c].x - m));
    w.y = f2bf(__expf(v[c].y - m));
    w.z = f2bf(__expf(v[c].z - m));
    w.w = f2bf(__expf(v[c].w - m));
    *(ushort4*)&P[(size_t)row * LB + (c * 256 + tid) * 4] = w;
  }
  float4 z = {0.f, 0.f, 0.f, 0.f};
  *(float4*)&wa[(size_t)row * DD + tid * 4] = z;
}

// ---------------- column softmax stats --------------------------------------
__global__ __launch_bounds__(256) void col_partial(const float* __restrict__ E,
                                                   float* __restrict__ pmax,
                                                   float* __restrict__ psum) {
  const int c = blockIdx.x * 256 + threadIdx.x;
  const int rg = blockIdx.y;
  const float* e = E + (size_t)rg * 128 * LB + c;
  float m = -__builtin_inff(), s = 0.f;
#pragma unroll 4
  for (int r = 0; r < 128; ++r) {
    const float x = e[(size_t)r * LB];
    const float nm = fmaxf(m, x);
    s = s * __expf(m - nm) + __expf(x - nm);
    m = nm;
  }
  pmax[rg * LB + c] = m;
  psum[rg * LB + c] = s;
}

__global__ __launch_bounds__(256) void col_combine(const float* __restrict__ pmax,
                                                   const float* __restrict__ psum,
                                                   float* __restrict__ cmax,
                                                   float* __restrict__ cinv) {
  const int c = blockIdx.x * 256 + threadIdx.x;
  float m = -__builtin_inff(), s = 0.f;
#pragma unroll 4
  for (int g = 0; g < 32; ++g) {
    const float pm = pmax[g * LB + c], ps = psum[g * LB + c];
    const float nm = fmaxf(m, pm);
    s = s * __expf(m - nm) + ps * __expf(pm - nm);
    m = nm;
  }
  cmax[c] = m;
  cinv[c] = 1.f / s;
}

// ---- Pb[j][i] = bf16(exp(E[i][j] - cmax[j])), transposing ------------------
__global__ __launch_bounds__(256) void make_pb(const float* __restrict__ E,
                                               const float* __restrict__ cmax,
                                               u16* __restrict__ P) {
  __shared__ u16 t[32][33];
  const int j0 = blockIdx.x * 32;
  const int i0 = blockIdx.y * 32;
  const int tid = threadIdx.x;
  const int lr = tid >> 3, lc = (tid & 7) * 4;
  const float4 v = *(const float4*)&E[(size_t)(i0 + lr) * LB + j0 + lc];
  const float4 cm = *(const float4*)&cmax[j0 + lc];
  t[lr][lc + 0] = f2bf(__expf(v.x - cm.x));
  t[lr][lc + 1] = f2bf(__expf(v.y - cm.y));
  t[lr][lc + 2] = f2bf(__expf(v.z - cm.z));
  t[lr][lc + 3] = f2bf(__expf(v.w - cm.w));
  __syncthreads();
  ushort4 w;
  w.x = t[lc + 0][lr]; w.y = t[lc + 1][lr]; w.z = t[lc + 2][lr]; w.w = t[lc + 3][lr];
  *(ushort4*)&P[(size_t)(j0 + lr) * LA + i0 + lc] = w;
}

// ---------------- zero helper for atomic split-K ----------------------------
__global__ __launch_bounds__(256) void wb_zero(float* __restrict__ w) {
  const size_t idx = ((size_t)blockIdx.x * 256 + threadIdx.x) * 8;
  const float4 z = {0.f, 0.f, 0.f, 0.f};
  *(float4*)&w[idx] = z;
  *(float4*)&w[idx + 4] = z;
}

// ---------------- elementwise finish (FP32 out): copy / a-w / a*w -----------
__global__ __launch_bounds__(256) void finish(const float* __restrict__ Ain,
                                              const float* __restrict__ Bin,
                                              float* __restrict__ out) {
  const int side = blockIdx.x >> 11;
  const int blk = blockIdx.x & 2047;
  const size_t idx = ((size_t)blk * 256 + threadIdx.x) * 8;
  const size_t S = (size_t)LA * DD;
  const float* src = side ? Bin : Ain;
  float* ob = out + (size_t)side * 4 * S;
  const float4 a0 = *(const float4*)&src[idx];
  const float4 a1 = *(const float4*)&src[idx + 4];
  const float4 w0 = *(const float4*)&ob[S + idx];
  const float4 w1 = *(const float4*)&ob[S + idx + 4];
  float4 s0, s1, m0, m1;
  s0.x = a0.x - w0.x; s0.y = a0.y - w0.y; s0.z = a0.z - w0.z; s0.w = a0.w - w0.w;
  s1.x = a1.x - w1.x; s1.y = a1.y - w1.y; s1.z = a1.z - w1.z; s1.w = a1.w - w1.w;
  m0.x = a0.x * w0.x; m0.y = a0.y * w0.y; m0.z = a0.z * w0.z; m0.w = a0.w * w0.w;
  m1.x = a1.x * w1.x; m1.y = a1.y * w1.y; m1.z = a1.z * w1.z; m1.w = a1.w * w1.w;
  *(float4*)&ob[idx] = a0;            *(float4*)&ob[idx + 4] = a1;
  *(float4*)&ob[2 * S + idx] = s0;    *(float4*)&ob[2 * S + idx + 4] = s1;
  *(float4*)&ob[3 * S + idx] = m0;    *(float4*)&ob[3 * S + idx + 4] = m1;
}

extern "C" void kernel_launch(void* const* d_in, const int* in_sizes, int n_in,
                              void* d_out, int out_size, void* d_ws, size_t ws_size,
                              hipStream_t stream) {
  const float* A = (const float*)d_in[0];
  const float* B = (const float*)d_in[1];
  float* out = (float*)d_out;          // FP32 output: 8 slots of S floats
  const size_t S = (size_t)LA * DD;    // 4,194,304

  // Scratch choreography inside the 128 MiB fp32 out buffer:
  //   slot0: stats (1.1MB) + Bt (u16 at float-ofs 1M); finish side0 copy LAST
  //   slot1 + [2S,2.5S): A' (24MB) during energy; slot1 -> wave_a after
  //   [2.5S,4S): B' (24MB) during energy; [2S,4S) -> P (32MB) after
  //   [4S,8S): E (64MB) -> then At (4S..4.5S), wave_b (5S..6S), finish side1
  float* pmax = out;                       // 131072
  float* psum = pmax + 131072;             // 131072
  float* rmax = psum + 131072;             // unused, layout keeper
  float* rinv = rmax + 4096;
  float* cmax = rinv + 4096;
  float* cinv = cmax + 4096;
  u16*   Bt   = (u16*)(out + 1048576);     // [DD][LB] u16, 8MB
  u16*   Ap   = (u16*)(out + S);           // [LA][3072] u16, 24MB
  u16*   Bp   = Ap + (size_t)LA * 3072;    // [LB][3072] u16, 24MB
  u16*   P    = (u16*)(out + 2 * S);       // [4096][4096] u16 (after A'/B' dead)
  float* E    = out + 4 * S;               // [4096][4096] fp32, 64MB
  u16*   At   = (u16*)(out + 4 * S);       // [DD][LA] u16 (after E consumed)
  float* wave_a = out + S;
  float* wave_b = out + 5 * S;

  split_ab<<<dim3(4096), 256, 0, stream>>>(A, B, Ap, Bp);
  gemm8<0><<<dim3(LB / 256, LA / 256), 512, 0, stream>>>(Ap, Bp, nullptr, E, 3072, LB, 3072);

  // row softmax + Pa in ONE E pass; also zeroes wave_a for the atomic PV
  row_softmax_pa<<<dim3(LA), 256, 0, stream>>>(E, rinv, P, wave_a);
  col_partial<<<dim3(LB / 256, 32), 256, 0, stream>>>(E, pmax, psum);
  col_combine<<<dim3(LB / 256), 256, 0, stream>>>(pmax, psum, cmax, cinv);

  // wave_a: split-K x4 atomic into pre-zeroed slot1
  tr_f32<<<dim3(DD / 32, LB / 32), 256, 0, stream>>>(B, Bt, LB, DD);
  gemm8<1><<<dim3(DD / 256, LA / 256, 4), 512, 0, stream>>>(P, Bt, rinv, wave_a, 4096, DD, 1024);

  // wave_b: split-K x4 atomic into zeroed slot5
  make_pb<<<dim3(LB / 32, LA / 32), 256, 0, stream>>>(E, cmax, P);
  tr_f32<<<dim3(DD / 32, LA / 32), 256, 0, stream>>>(A, At, LA, DD);
  wb_zero<<<dim3(2048), 256, 0, stream>>>(wave_b);
  gemm8<1><<<dim3(DD / 256, LB / 256, 4), 512, 0, stream>>>(P, At, cinv, wave_b, 4096, DD, 1024);

  finish<<<dim3(4096), 256, 0, stream>>>(A, B, out);
}